// Round 3
// baseline (322.692 us; speedup 1.0000x reference)
//
#include <hip/hip_runtime.h>
#include <math.h>

// Problem constants (from reference)
#define NG   1024        // graphs
#define NP   256         // nodes per graph
#define EPG  4096        // edges per graph
#define ETOT 4194304     // total edges
#define NTOT (NG * NP)   // 262144 nodes
#define FIN  7
#define HD   64
#define KC   50
#define CHK  64          // rows per phase-2 chunk
#define FST  72          // f16 LDS row stride for 64x64 tiles (36w = 4 mod 32)
#define PST  64          // Pf fp32 row stride
#define TSC  0.00390625f // tail scale 1/256 (exact)
#define TSCI 256.0f      // inverse

// ST (S^T [k][n]) and A-slab use stride 256 halves with XOR swizzle:
// half index ^= (row&7)<<3  (16B blocks permuted within each 128B stripe).
// Write side and read side use the SAME formula (both-sides-or-neither).
#define SW_ST(k, n)  ((k) * 256 + ((n) ^ (((k) & 7) << 3)))   // half idx
#define SW_AW(r, w)  ((r) * 128 + ((w) ^ (((r) & 7) << 2)))   // word idx
#define SW_AH(r, h)  ((r) * 256 + ((h) ^ (((r) & 7) << 3)))   // half idx

// NOTE (R2..R16 prior session): sort-gather, MFMA GEMMs, dense-A slabs,
// fused tail, 1/256 tail scaling for f16 range.
// NOTE (R1): fused k1a+k2+k3 into one per-graph megakernel; total 321->316.
// NOTE (R2): counters said latency-bound (HBM 1.2%, Mfma 3.8%, VALU 34%,
// occ 45.7%): 16-wave lockstep, 1 block/CU, every barrier drain exposed.
// Shrunk LDS 127.5KB -> ~79KB for 2 blocks/CU: HT deleted (xp accumulated in
// phase 2 from per-chunk hTc), cells -> 4 regs/thread, ST/A stride 256+XOR
// swizzle, xagg f16, Pf stride 64. __expf/__logf in softmax.

typedef __attribute__((ext_vector_type(8))) _Float16 v8h;
typedef __attribute__((ext_vector_type(4))) float v4f;

// f16 preconverted weights (rewritten every launch; capture-safe)
__device__ __align__(16) _Float16 g_W1bT[HD * HD];          // W1b^T [d][j]
__device__ __align__(16) _Float16 g_WpT[HD * HD];           // Wp^T  [k][d]
__device__ __align__(16) _Float16 g_W2aT[HD * HD];          // W2a^T [d2][d]
__device__ __align__(16) _Float16 g_W2bT[HD * HD];          // W2b^T [j][d2]

__global__ void zero_ws(float* ws) {
    if (threadIdx.x < 4) ws[threadIdx.x] = 0.f;
}

__global__ void kw_conv(const float* __restrict__ W1b, const float* __restrict__ Wp,
                        const float* __restrict__ W2a, const float* __restrict__ W2b) {
    const int tid = threadIdx.x;
    for (int i = tid; i < HD * HD; i += 1024) {
        int d = i >> 6, j = i & 63;
        g_W1bT[i] = (_Float16)W1b[j * HD + d];      // [d][j]
        g_W2aT[i] = (_Float16)W2a[j * HD + d];      // [d2][d]
        g_W2bT[i] = (_Float16)W2b[j * HD + d];      // [j][d2]
    }
    for (int i = tid; i < HD * HD; i += 1024) {
        int k = i >> 6, d = i & 63;
        g_WpT[i] = (k < KC) ? (_Float16)Wp[d * KC + k] : (_Float16)0.f;
    }
}

// ws[0]=sumA2, ws[1]=sum S logS, ws[2]=trace(Ap), ws[3]=||G||^2
__global__ void finalize_k(const float* __restrict__ ws, float* __restrict__ out) {
    if (threadIdx.x == 0) {
        float num = ws[0] - 2.f * ws[2] + ws[3];
        float link = sqrtf(fmaxf(num, 0.f)) / 67108864.0f;   // / (B*n*n)
        float ent  = -ws[1] / 262144.0f;                     // / N
        out[2048] = link + ent;
    }
}

__device__ __forceinline__ float blockReduceN(float v, float* red, int nw) {
    __syncthreads();
    #pragma unroll
    for (int o = 32; o > 0; o >>= 1) v += __shfl_down(v, o);
    if ((threadIdx.x & 63) == 0) red[threadIdx.x >> 6] = v;
    __syncthreads();
    float r = 0.f;
    if (threadIdx.x == 0) {
        for (int i = 0; i < nw; ++i) r += red[i];
    }
    return r;
}

// ---- MEGA: per-graph fused pipeline, 2 blocks/CU ----------------------------
// Phase 1: edge decode + di counting sort + gather GIN agg  -> xagg (LDS f16)
// Phase 2: MLP1 + h-GEMM + P-GEMM + softmax + xp-GEMM       -> ST (LDS), axp
// Phase 3: dense-A slabs + AS/Ap/G MFMA + dense-GIN head    -> out
__launch_bounds__(1024, 2)
__global__ void mega(const int* __restrict__ esrc, const int* __restrict__ edst,
                     const float* __restrict__ x,
                     const float* __restrict__ W1a, const float* __restrict__ b1a,
                     const float* __restrict__ b1b, const float* __restrict__ bp,
                     const float* __restrict__ b2a, const float* __restrict__ b2b,
                     const float* __restrict__ Wl,  const float* __restrict__ bl,
                     float* __restrict__ out, float* __restrict__ ws)
{
    __shared__ __align__(16) _Float16 ST[64 * 256];   // 32 KB  S^T [k][n] swz
    __shared__ __align__(16) _Float16 xagg[NP * 8];   // 4 KB   x+agg f16
    __shared__ __align__(16) union {
        struct {                                      // phase 1 (15.4 KB)
            unsigned char ssi[EPG];
            float xt8[NP * 8];
            unsigned int hist[256], cur[256], roff[NP + 1];
        } k1;
        struct {                                      // phase 2 (44 KB)
            _Float16 t1b[CHK * FST];                  // t1   [n][j]
            _Float16 hN[CHK * FST];                   // h    [n][d]
            _Float16 hTc[HD * FST];                   // h^T  [d][n] (chunk)
            float Pf[CHK * PST];                      // P    [n][k]
        } k2;
        struct {                                      // phase 3 slab (41 KB)
            unsigned int cnt[64 * 128];               // A slab, swizzled words
            _Float16 T1T[64 * FST];                   // AS^T [c][nrow]
        } a;
        struct {                                      // phase 3 tail (36.9 KB)
            _Float16 Apf[64 * FST];
            _Float16 xpT[64 * FST];
            _Float16 h2f[64 * FST];
            _Float16 tf[64 * FST];
        } b;
    } u;
    __shared__ float red[16];

    const int g = blockIdx.x, tid = threadIdx.x;
    const int lane = tid & 63, wid = tid >> 6;        // wid 0..15
    const int l15 = lane & 15, quad = lane >> 4, fko = quad * 8;
    const int mt = (wid >> 2) << 4, nt = (wid & 3) << 4;

    // ---- init: zero ST (rows k>=50 must stay 0 for phase 2/3 MFMAs) ----
    for (int i = tid; i < 64 * 128; i += 1024) ((unsigned int*)ST)[i] = 0u;
    if (tid < 256) u.k1.hist[tid] = 0u;
    __syncthreads();

    // ---- phase 1: decode edges (into regs) + histogram + stage x ----
    unsigned int cellr[4];                            // this thread's 4 edges
    #pragma unroll
    for (int j = 0; j < 4; ++j) {
        int e = tid + j * 1024;
        int s = esrc[g * EPG + e] & (NP - 1);
        int d = edst[g * EPG + e] & (NP - 1);
        cellr[j] = (unsigned)((s << 8) | d);
        atomicAdd(&u.k1.hist[d], 1u);
    }
    for (int i = tid; i < NP * 8; i += 1024) {
        int n = i >> 3, f = i & 7;
        u.k1.xt8[i] = (f < FIN) ? x[g * NP * FIN + n * FIN + f] : 0.f;
    }
    __syncthreads();

    // exclusive scan (wave 0)
    if (wid == 0) {
        unsigned carry = 0;
        for (int c = 0; c < 4; ++c) {
            unsigned v = u.k1.hist[c * 64 + lane];
            unsigned s = v;
            #pragma unroll
            for (int o = 1; o < 64; o <<= 1) {
                unsigned t = __shfl_up(s, o);
                if (lane >= o) s += t;
            }
            unsigned excl = s - v + carry;
            u.k1.roff[c * 64 + lane] = excl;
            u.k1.cur[c * 64 + lane] = excl;
            carry += __shfl(s, 63);
        }
        if (lane == 0) u.k1.roff[NP] = EPG;
    }
    __syncthreads();

    #pragma unroll
    for (int j = 0; j < 4; ++j) {
        unsigned c = cellr[j];
        unsigned p2 = atomicAdd(&u.k1.cur[c & 255u], 1u);
        u.k1.ssi[p2] = (unsigned char)(c >> 8);
    }
    __syncthreads();

    // gather agg: 8 lanes per node -> xagg (f16)
    {
        const int gi = tid >> 3, f = tid & 7;
        for (int n = gi; n < NP; n += 128) {
            int beg = u.k1.roff[n], end = u.k1.roff[n + 1];
            float a = u.k1.xt8[n * 8 + f];
            for (int e = beg; e < end; ++e)
                a += u.k1.xt8[u.k1.ssi[e] * 8 + f];
            xagg[n * 8 + f] = (_Float16)a;
        }
    }
    __syncthreads();

    // ---- phase 2: MLP1 + h + P + softmax + xp, 4 chunks of 64 rows ----
    float entL = 0.f;
    v4f axp = {0.f, 0.f, 0.f, 0.f};                   // xp tile (accum here)
    {
        float w1r[FIN];
        #pragma unroll
        for (int f = 0; f < FIN; ++f) w1r[f] = W1a[f * HD + lane];
        float b1r = b1a[lane];

        for (int ch2 = 0; ch2 < 4; ++ch2) {
            const int rb = ch2 * 64;
            // t1 = relu((x+agg) @ W1a + b1a)   [writes t1b; xp(ch2-1) done]
            for (int n = wid; n < CHK; n += 16) {
                float a = b1r;
                #pragma unroll
                for (int f = 0; f < FIN; ++f)
                    a += (float)xagg[(rb + n) * 8 + f] * w1r[f];
                u.k2.t1b[n * FST + lane] = (_Float16)fmaxf(a, 0.f);
            }
            __syncthreads();

            // h = t1 @ W1b + b1b  (1 tile/wave; B-frag from L2-hot global)
            {
                v4f acc = {0.f, 0.f, 0.f, 0.f};
                #pragma unroll
                for (int ks = 0; ks < 2; ++ks) {
                    v8h af = *(const v8h*)&u.k2.t1b[(mt + l15) * FST + ks * 32 + fko];
                    v8h bf = *(const v8h*)&g_W1bT[(nt + l15) * HD + ks * 32 + fko];
                    acc = __builtin_amdgcn_mfma_f32_16x16x32_f16(af, bf, acc, 0, 0, 0);
                }
                int d = nt + l15;
                float bv = b1b[d];
                #pragma unroll
                for (int r = 0; r < 4; ++r) {
                    int m = mt + quad * 4 + r;
                    _Float16 hv = (_Float16)(acc[r] + bv);
                    u.k2.hN[m * FST + d] = hv;
                    u.k2.hTc[d * FST + m] = hv;       // chunk h^T for xp-GEMM
                }
            }
            __syncthreads();

            // P = h @ Wp + bp
            {
                v4f acc = {0.f, 0.f, 0.f, 0.f};
                #pragma unroll
                for (int ks = 0; ks < 2; ++ks) {
                    v8h af = *(const v8h*)&u.k2.hN[(mt + l15) * FST + ks * 32 + fko];
                    v8h bf = *(const v8h*)&g_WpT[(nt + l15) * HD + ks * 32 + fko];
                    acc = __builtin_amdgcn_mfma_f32_16x16x32_f16(af, bf, acc, 0, 0, 0);
                }
                int kcol = nt + l15;
                if (kcol < KC) {
                    float bv = bp[kcol];
                    #pragma unroll
                    for (int r = 0; r < 4; ++r)
                        u.k2.Pf[(mt + quad * 4 + r) * PST + kcol] = acc[r] + bv;
                }
            }
            __syncthreads();

            // softmax rows -> ST (swizzled), entropy partial
            for (int n = wid; n < CHK; n += 16) {
                float a = (lane < KC) ? u.k2.Pf[n * PST + lane] : -INFINITY;
                float m = a;
                #pragma unroll
                for (int o = 32; o > 0; o >>= 1) m = fmaxf(m, __shfl_xor(m, o));
                float e = __expf(a - m);
                float ss = e;
                #pragma unroll
                for (int o = 32; o > 0; o >>= 1) ss += __shfl_xor(ss, o);
                float s = e / ss;
                if (lane < KC) {
                    ST[SW_ST(lane, rb + n)] = (_Float16)s;
                    entL += s * __logf(s + 1e-15f);
                }
            }
            __syncthreads();

            // xp += S_chunk^T @ h_chunk  (reads ST chunk + hTc; no sync after:
            // next t1 writes only t1b; next h-GEMM (after barrier) reuses hTc)
            {
                const int ar = mt + l15, br = nt + l15;
                #pragma unroll
                for (int ks = 0; ks < 2; ++ks) {
                    v8h af = *(const v8h*)&ST[SW_ST(ar, rb + ks * 32 + fko)];
                    v8h bf = *(const v8h*)&u.k2.hTc[br * FST + ks * 32 + fko];
                    axp = __builtin_amdgcn_mfma_f32_16x16x32_f16(af, bf, axp, 0, 0, 0);
                }
            }
        }
    }
    {
        float rE = blockReduceN(entL, red, 16);       // barriers fence u reuse
        if (tid == 0) atomicAdd(&ws[1], rE);
    }

    // ---- phase 3: dense-A slabs + MFMA AS/Ap/G ----
    float sumA2 = 0.f;
    v4f ap = {0.f, 0.f, 0.f, 0.f};
    v4f ag = {0.f, 0.f, 0.f, 0.f};

    for (int ch = 0; ch < 4; ++ch) {
        for (int i = tid; i < 64 * 128; i += 1024) u.a.cnt[i] = 0u;
        __syncthreads();

        int rlo = ch << 6;
        #pragma unroll
        for (int j = 0; j < 4; ++j) {
            unsigned c = cellr[j];
            int sr = (int)(c >> 8) - rlo;
            if ((unsigned)sr < 64u) {
                int d = c & 255u;
                atomicAdd(&u.a.cnt[SW_AW(sr, d >> 1)],
                          (d & 1) ? 0x10000u : 1u);
            }
        }
        __syncthreads();

        // sum(A^2) partial + in-place convert counts -> f16 (elementwise)
        for (int i = tid; i < 64 * 128; i += 1024) {
            unsigned v = u.a.cnt[i];
            float m0 = (float)(v & 0xffffu), m1 = (float)(v >> 16);
            sumA2 += m0 * m0 + m1 * m1;
            union { unsigned uu; _Float16 h[2]; } cv;
            cv.h[0] = (_Float16)m0; cv.h[1] = (_Float16)m1;
            u.a.cnt[i] = cv.uu;
        }
        __syncthreads();

        const _Float16* Af = (const _Float16*)u.a.cnt;

        // AS_slab = A_slab @ S  (both operands swizzled-read)
        {
            const int ar = mt + l15, br = nt + l15;
            v4f acc = {0.f, 0.f, 0.f, 0.f};
            #pragma unroll
            for (int ks = 0; ks < 8; ++ks) {
                v8h af = *(const v8h*)&Af[SW_AH(ar, ks * 32 + fko)];
                v8h bf = *(const v8h*)&ST[SW_ST(br, ks * 32 + fko)];
                acc = __builtin_amdgcn_mfma_f32_16x16x32_f16(af, bf, acc, 0, 0, 0);
            }
            int c = nt + l15;
            #pragma unroll
            for (int r = 0; r < 4; ++r)
                u.a.T1T[c * FST + mt + quad * 4 + r] = (_Float16)acc[r];
        }
        __syncthreads();

        // Ap += S_slab^T @ AS_slab; G += S^T S (slab K-range)
        {
            const int ar = mt + l15, br = nt + l15;
            #pragma unroll
            for (int ks = 0; ks < 2; ++ks) {
                int ko = (ch << 6) + ks * 32 + fko;
                v8h af = *(const v8h*)&ST[SW_ST(ar, ko)];
                v8h bt = *(const v8h*)&u.a.T1T[br * FST + ks * 32 + fko];
                v8h bs = *(const v8h*)&ST[SW_ST(br, ko)];
                ap = __builtin_amdgcn_mfma_f32_16x16x32_f16(af, bt, ap, 0, 0, 0);
                ag = __builtin_amdgcn_mfma_f32_16x16x32_f16(af, bs, ag, 0, 0, 0);
            }
        }
        __syncthreads();    // u.a reused next slab
    }

    // scalars + f16 Ap / xp^T into tail buffers
    float tr = 0.f, g2 = 0.f;
    {
        int c = nt + l15;
        #pragma unroll
        for (int r = 0; r < 4; ++r) {
            int k = mt + quad * 4 + r;
            u.b.Apf[k * FST + c] = (_Float16)ap[r];
            u.b.xpT[c * FST + k] = (_Float16)axp[r];
            if (k < KC && c < KC) {
                if (k == c) tr += ap[r];
                g2 += ag[r] * ag[r];
            }
        }
    }

    float rA = blockReduceN(sumA2, red, 16);   // internal barriers fence u.b
    float rT = blockReduceN(tr, red, 16);
    float rG = blockReduceN(g2, red, 16);
    if (tid == 0) {
        atomicAdd(&ws[0], rA);
        atomicAdd(&ws[2], rT);
        atomicAdd(&ws[3], rG);
    }
    __syncthreads();

    // ---- MFMA tail: h2 = xp + Ap @ xp, scaled by 1/256 ----
    {
        v4f hacc = axp;
        #pragma unroll
        for (int ks = 0; ks < 2; ++ks) {
            v8h af = *(const v8h*)&u.b.Apf[(mt + l15) * FST + ks * 32 + fko];
            v8h bf = *(const v8h*)&u.b.xpT[(nt + l15) * FST + ks * 32 + fko];
            hacc = __builtin_amdgcn_mfma_f32_16x16x32_f16(af, bf, hacc, 0, 0, 0);
        }
        int d = nt + l15;
        #pragma unroll
        for (int r = 0; r < 4; ++r)
            u.b.h2f[(mt + quad * 4 + r) * FST + d] = (_Float16)(hacc[r] * TSC);
    }
    __syncthreads();

    // t*s = relu(h2s @ W2a + s*b2a)
    {
        float bv = b2a[nt + l15] * TSC;
        v4f tacc = {bv, bv, bv, bv};
        #pragma unroll
        for (int ks = 0; ks < 2; ++ks) {
            v8h af = *(const v8h*)&u.b.h2f[(mt + l15) * FST + ks * 32 + fko];
            v8h bf = *(const v8h*)&g_W2aT[(nt + l15) * 64 + ks * 32 + fko];
            tacc = __builtin_amdgcn_mfma_f32_16x16x32_f16(af, bf, tacc, 0, 0, 0);
        }
        int d2 = nt + l15;
        #pragma unroll
        for (int r = 0; r < 4; ++r)
            u.b.tf[(mt + quad * 4 + r) * FST + d2] = (_Float16)fmaxf(tacc[r], 0.f);
    }
    __syncthreads();

    // h3 = (t*s)@W2b * 256 + b2b; fold mean over k and Wl in fp32
    float l0 = 0.f, l1 = 0.f;
    {
        v4f oacc = {0.f, 0.f, 0.f, 0.f};
        #pragma unroll
        for (int ks = 0; ks < 2; ++ks) {
            v8h af = *(const v8h*)&u.b.tf[(mt + l15) * FST + ks * 32 + fko];
            v8h bf = *(const v8h*)&g_W2bT[(nt + l15) * 64 + ks * 32 + fko];
            oacc = __builtin_amdgcn_mfma_f32_16x16x32_f16(af, bf, oacc, 0, 0, 0);
        }
        int j = nt + l15;
        float bv = b2b[j];
        float wl0 = Wl[j * 2], wl1 = Wl[j * 2 + 1];
        #pragma unroll
        for (int r = 0; r < 4; ++r) {
            int k = mt + quad * 4 + r;
            if (k < KC) {
                float h3v = oacc[r] * TSCI + bv;
                l0 += h3v * wl0; l1 += h3v * wl1;
            }
        }
    }

    float rl0 = blockReduceN(l0, red, 16);
    float rl1 = blockReduceN(l1, red, 16);
    if (tid == 0) {
        float g0 = bl[0] + rl0 * (1.f / KC);
        float g1 = bl[1] + rl1 * (1.f / KC);
        float mm = fmaxf(g0, g1);
        float lse = mm + logf(expf(g0 - mm) + expf(g1 - mm));
        out[2 * g]     = g0 - lse;
        out[2 * g + 1] = g1 - lse;
    }
}

extern "C" void kernel_launch(void* const* d_in, const int* in_sizes, int n_in,
                              void* d_out, int out_size, void* d_ws, size_t ws_size,
                              hipStream_t stream) {
    const float* x    = (const float*)d_in[0];
    const float* W1a  = (const float*)d_in[1];
    const float* b1a  = (const float*)d_in[2];
    const float* W1b  = (const float*)d_in[3];
    const float* b1b  = (const float*)d_in[4];
    const float* Wp   = (const float*)d_in[5];
    const float* bp   = (const float*)d_in[6];
    const float* W2a  = (const float*)d_in[7];
    const float* b2a  = (const float*)d_in[8];
    const float* W2b  = (const float*)d_in[9];
    const float* b2b  = (const float*)d_in[10];
    const float* Wl   = (const float*)d_in[11];
    const float* bl   = (const float*)d_in[12];
    const int*   eidx = (const int*)d_in[13];   // [2, E] int32
    float* out = (float*)d_out;
    float* ws  = (float*)d_ws;

    zero_ws<<<1, 64, 0, stream>>>(ws);
    kw_conv<<<1, 1024, 0, stream>>>(W1b, Wp, W2a, W2b);
    mega<<<NG, 1024, 0, stream>>>(eidx, eidx + ETOT, x,
                                  W1a, b1a, b1b, bp,
                                  b2a, b2b, Wl, bl, out, ws);
    finalize_k<<<1, 64, 0, stream>>>(ws, out);
}

// Round 4
// 293.766 us; speedup vs baseline: 1.0985x; 1.0985x over previous
//
#include <hip/hip_runtime.h>
#include <math.h>

// Problem constants (from reference)
#define NG   1024        // graphs
#define NP   256         // nodes per graph
#define EPG  4096        // edges per graph
#define ETOT 4194304     // total edges
#define NTOT (NG * NP)   // 262144 nodes
#define FIN  7
#define HD   64
#define KC   50
#define CHK  64          // rows per phase-2 chunk
#define FST  72          // f16 LDS row stride for 64x64 tiles (36w = 4 mod 32)
#define TSC  0.00390625f // tail scale 1/256 (exact)
#define TSCI 256.0f      // inverse

// ST (S^T [k][n]) and A-slab: stride 256 halves with XOR swizzle, write and
// read sides use the SAME formula (both-sides-or-neither).
#define SW_ST(k, n)  ((k) * 256 + ((n) ^ (((k) & 7) << 3)))   // half idx
#define SW_AW(r, w)  ((r) * 128 + ((w) ^ (((r) & 7) << 2)))   // word idx
#define SW_AH(r, h)  ((r) * 256 + ((h) ^ (((r) & 7) << 3)))   // half idx

// NOTE (R1): fused k1a+k2+k3 into per-graph megakernel; 321 -> 316 total.
// NOTE (R2): latency-bound (HBM 1.2%, Mfma 3.8%, occ 46%); shrank LDS 127->81KB.
// NOTE (R3): occupancy did NOT double at 81.4KB/block (2x = 162.8KB vs 160KB
// cap + unknown reserve?) and phase-2 adds regressed mega 219->241. This
// round: h never materialized -- P = t1@(W1b Wp)+bP', xp = (S^T t1)@W1b +
// colsum(S) (x) b1b. LDS -> ~73KB (15KB headroom for 2 blocks/CU).
// kw_conv: 16 blocks, zero_ws folded in.

typedef __attribute__((ext_vector_type(8))) _Float16 v8h;
typedef __attribute__((ext_vector_type(4))) float v4f;

// f16 preconverted weights (rewritten every launch; capture-safe)
__device__ __align__(16) _Float16 g_W1bT[HD * HD];   // W1b^T [d][j]
__device__ __align__(16) _Float16 g_WWT[HD * HD];    // (W1b@Wp)^T [k][j]
__device__ __align__(16) _Float16 g_W2aT[HD * HD];   // W2a^T [d2][d]
__device__ __align__(16) _Float16 g_W2bT[HD * HD];   // W2b^T [j][d2]
__device__ float g_bP[HD];                           // b1b@Wp + bp (pad 0)

// kw_conv: 16 blocks x 256 thr. Transposes + WW fold + bP + ws zero.
__global__ void kw_conv(const float* __restrict__ W1b, const float* __restrict__ Wp,
                        const float* __restrict__ W2a, const float* __restrict__ W2b,
                        const float* __restrict__ b1b, const float* __restrict__ bp,
                        float* __restrict__ ws) {
    const int b = blockIdx.x, tid = threadIdx.x;
    if (b == 0 && tid < 4) ws[tid] = 0.f;
    {   // transposes: element i of 4096
        int i = b * 256 + tid;
        int d = i >> 6, j = i & 63;
        g_W1bT[i] = (_Float16)W1b[j * HD + d];
        g_W2aT[i] = (_Float16)W2a[j * HD + d];
        g_W2bT[i] = (_Float16)W2b[j * HD + d];
    }
    {   // WW^T[k][j] = sum_d W1b[j][d] Wp[d][k]; rows k>=KC stay 0
        int k = b * 4 + (tid >> 6), j = tid & 63;
        float acc = 0.f;
        if (k < KC) {
            for (int d = 0; d < HD; ++d)
                acc += W1b[j * HD + d] * Wp[d * KC + k];
        }
        g_WWT[k * HD + j] = (_Float16)acc;
    }
    if (tid < 4) {      // bP[k] = sum_d b1b[d] Wp[d][k] + bp[k]
        int k = b * 4 + tid;
        float a = 0.f;
        if (k < KC) {
            for (int d = 0; d < HD; ++d) a += b1b[d] * Wp[d * KC + k];
            a += bp[k];
        }
        g_bP[k] = a;
    }
}

// ws[0]=sumA2, ws[1]=sum S logS, ws[2]=trace(Ap), ws[3]=||G||^2
__global__ void finalize_k(const float* __restrict__ ws, float* __restrict__ out) {
    if (threadIdx.x == 0) {
        float num = ws[0] - 2.f * ws[2] + ws[3];
        float link = sqrtf(fmaxf(num, 0.f)) / 67108864.0f;   // / (B*n*n)
        float ent  = -ws[1] / 262144.0f;                     // / N
        out[2048] = link + ent;
    }
}

__device__ __forceinline__ float blockReduceN(float v, float* red, int nw) {
    __syncthreads();
    #pragma unroll
    for (int o = 32; o > 0; o >>= 1) v += __shfl_down(v, o);
    if ((threadIdx.x & 63) == 0) red[threadIdx.x >> 6] = v;
    __syncthreads();
    float r = 0.f;
    if (threadIdx.x == 0) {
        for (int i = 0; i < nw; ++i) r += red[i];
    }
    return r;
}

// ---- MEGA: per-graph fused pipeline, target 2 blocks/CU ---------------------
// Phase 1: edge decode + di counting sort + gather GIN agg  -> xagg (aux)
// Phase 2: t1 -> P(fused W) -> softmax -> SP += S^T t1      -> ST, SPacc
//          then xp = SP @ W1b + colsum(S) (x) b1b           -> axp (regs)
// Phase 3: dense-A slabs + AS/Ap/G MFMA + dense-GIN head    -> out
__launch_bounds__(1024, 2)
__global__ void mega(const int* __restrict__ esrc, const int* __restrict__ edst,
                     const float* __restrict__ x,
                     const float* __restrict__ W1a, const float* __restrict__ b1a,
                     const float* __restrict__ b1b,
                     const float* __restrict__ b2a, const float* __restrict__ b2b,
                     const float* __restrict__ Wl,  const float* __restrict__ bl,
                     float* __restrict__ out, float* __restrict__ ws)
{
    __shared__ __align__(16) _Float16 ST[64 * 256];   // 32 KB  S^T [k][n] swz
    __shared__ __align__(16) unsigned char aux[9216]; // xagg(ph1-2) | T1T(ph3)
    __shared__ __align__(16) union {
        struct {                                      // phase 1 (15.4 KB)
            unsigned char ssi[EPG];
            float xt8[NP * 8];
            unsigned int hist[256], cur[256], roff[NP + 1];
        } k1;
        struct {                                      // phase 2 (27.6 KB)
            _Float16 t1b[CHK * FST];                  // t1 [n][j] (also SPb)
            _Float16 t1T[CHK * FST];                  // t1^T [j][n]
            _Float16 Pf[CHK * FST];                   // P  [n][k] f16
        } k2;
        struct {                                      // phase 3 slab (32 KB)
            unsigned int cnt[64 * 128];               // A slab, swizzled
        } a;
        struct {                                      // phase 3 tail (27.6 KB)
            _Float16 Apf_tf[64 * FST];                // Ap, later t*s
            _Float16 xpT[64 * FST];
            _Float16 h2f[64 * FST];
        } b;
    } u;
    __shared__ float cs[64];                          // colsum(S)
    __shared__ float red[16];

    float* xagg = (float*)aux;                        // [NP][8] f32 (8 KB)
    _Float16* T1T = (_Float16*)aux;                   // [64][FST] (9.2 KB)

    const int g = blockIdx.x, tid = threadIdx.x;
    const int lane = tid & 63, wid = tid >> 6;        // wid 0..15
    const int l15 = lane & 15, quad = lane >> 4, fko = quad * 8;
    const int mt = (wid >> 2) << 4, nt = (wid & 3) << 4;

    // ---- init: zero ST (rows k>=50 must stay 0 for phase 2/3 MFMAs) ----
    for (int i = tid; i < 64 * 128; i += 1024) ((unsigned int*)ST)[i] = 0u;
    if (tid < 256) u.k1.hist[tid] = 0u;
    __syncthreads();

    // ---- phase 1: decode edges (into regs) + histogram + stage x ----
    unsigned int cellr[4];
    #pragma unroll
    for (int j = 0; j < 4; ++j) {
        int e = tid + j * 1024;
        int s = esrc[g * EPG + e] & (NP - 1);
        int d = edst[g * EPG + e] & (NP - 1);
        cellr[j] = (unsigned)((s << 8) | d);
        atomicAdd(&u.k1.hist[d], 1u);
    }
    for (int i = tid; i < NP * 8; i += 1024) {
        int n = i >> 3, f = i & 7;
        u.k1.xt8[i] = (f < FIN) ? x[g * NP * FIN + n * FIN + f] : 0.f;
    }
    __syncthreads();

    // exclusive scan (wave 0)
    if (wid == 0) {
        unsigned carry = 0;
        for (int c = 0; c < 4; ++c) {
            unsigned v = u.k1.hist[c * 64 + lane];
            unsigned s = v;
            #pragma unroll
            for (int o = 1; o < 64; o <<= 1) {
                unsigned t = __shfl_up(s, o);
                if (lane >= o) s += t;
            }
            unsigned excl = s - v + carry;
            u.k1.roff[c * 64 + lane] = excl;
            u.k1.cur[c * 64 + lane] = excl;
            carry += __shfl(s, 63);
        }
        if (lane == 0) u.k1.roff[NP] = EPG;
    }
    __syncthreads();

    #pragma unroll
    for (int j = 0; j < 4; ++j) {
        unsigned c = cellr[j];
        unsigned p2 = atomicAdd(&u.k1.cur[c & 255u], 1u);
        u.k1.ssi[p2] = (unsigned char)(c >> 8);
    }
    __syncthreads();

    // gather agg: 8 lanes per node -> xagg (f32, aux region)
    {
        const int gi = tid >> 3, f = tid & 7;
        for (int n = gi; n < NP; n += 128) {
            int beg = u.k1.roff[n], end = u.k1.roff[n + 1];
            float a = u.k1.xt8[n * 8 + f];
            for (int e = beg; e < end; ++e)
                a += u.k1.xt8[u.k1.ssi[e] * 8 + f];
            xagg[n * 8 + f] = a;
        }
    }
    __syncthreads();

    // ---- phase 2: t1 -> P -> softmax -> SP, 4 chunks of 64 rows ----
    float entL = 0.f;
    v4f spa = {0.f, 0.f, 0.f, 0.f};                   // SP tile [k][j]
    {
        float w1r[FIN];
        #pragma unroll
        for (int f = 0; f < FIN; ++f) w1r[f] = W1a[f * HD + lane];
        float b1r = b1a[lane];

        for (int ch2 = 0; ch2 < 4; ++ch2) {
            const int rb = ch2 * 64;
            // t1 = relu((x+agg) @ W1a + b1a); write t1b [n][j] and t1T [j][n]
            for (int n = wid; n < CHK; n += 16) {
                float a = b1r;
                #pragma unroll
                for (int f = 0; f < FIN; ++f) a += xagg[(rb + n) * 8 + f] * w1r[f];
                _Float16 tv = (_Float16)fmaxf(a, 0.f);
                u.k2.t1b[n * FST + lane] = tv;
                u.k2.t1T[lane * FST + n] = tv;
            }
            __syncthreads();

            // P = t1 @ WW + bP  (fused W1b@Wp; B-frag from L2-hot global)
            {
                v4f acc = {0.f, 0.f, 0.f, 0.f};
                #pragma unroll
                for (int ks = 0; ks < 2; ++ks) {
                    v8h af = *(const v8h*)&u.k2.t1b[(mt + l15) * FST + ks * 32 + fko];
                    v8h bf = *(const v8h*)&g_WWT[(nt + l15) * HD + ks * 32 + fko];
                    acc = __builtin_amdgcn_mfma_f32_16x16x32_f16(af, bf, acc, 0, 0, 0);
                }
                int kcol = nt + l15;
                if (kcol < KC) {
                    float bv = g_bP[kcol];
                    #pragma unroll
                    for (int r = 0; r < 4; ++r)
                        u.k2.Pf[(mt + quad * 4 + r) * FST + kcol] =
                            (_Float16)(acc[r] + bv);
                }
            }
            __syncthreads();

            // softmax rows -> ST (swizzled), entropy partial
            for (int n = wid; n < CHK; n += 16) {
                float a = (lane < KC) ? (float)u.k2.Pf[n * FST + lane] : -INFINITY;
                float m = a;
                #pragma unroll
                for (int o = 32; o > 0; o >>= 1) m = fmaxf(m, __shfl_xor(m, o));
                float e = __expf(a - m);
                float ss = e;
                #pragma unroll
                for (int o = 32; o > 0; o >>= 1) ss += __shfl_xor(ss, o);
                float s = e / ss;
                if (lane < KC) {
                    ST[SW_ST(lane, rb + n)] = (_Float16)s;
                    entL += s * __logf(s + 1e-15f);
                }
            }
            __syncthreads();

            // SP += S_chunk^T @ t1_chunk  (af = ST rows k; bf = t1T rows j)
            {
                const int ar = mt + l15, br = nt + l15;
                #pragma unroll
                for (int ks = 0; ks < 2; ++ks) {
                    v8h af = *(const v8h*)&ST[SW_ST(ar, rb + ks * 32 + fko)];
                    v8h bf = *(const v8h*)&u.k2.t1T[br * FST + ks * 32 + fko];
                    spa = __builtin_amdgcn_mfma_f32_16x16x32_f16(af, bf, spa, 0, 0, 0);
                }
            }
            __syncthreads();    // t1b/t1T rewritten next chunk
        }
    }

    // SP tile -> SPb (reuses t1b region); colsum(S) partials -> cs
    {
        _Float16* SPb = u.k2.t1b;
        int c = nt + l15;
        #pragma unroll
        for (int r = 0; r < 4; ++r)
            SPb[(mt + quad * 4 + r) * FST + c] = (_Float16)spa[r];
    }
    {
        int k = tid >> 4, q = tid & 15;
        float v = 0.f;
        #pragma unroll
        for (int i = 0; i < 16; ++i) v += (float)ST[SW_ST(k, q * 16 + i)];
        #pragma unroll
        for (int o = 8; o > 0; o >>= 1) v += __shfl_xor(v, o);
        if (q == 0) cs[k] = v;
    }
    {
        float rE = blockReduceN(entL, red, 16);   // syncs fence SPb/cs writes
        if (tid == 0) atomicAdd(&ws[1], rE);
    }

    // xp = SP @ W1b + cs (x) b1b   (tile kept in regs through phase 3)
    v4f axp;
    {
        const int d = nt + l15;
        float bv = b1b[d];
        #pragma unroll
        for (int r = 0; r < 4; ++r) axp[r] = cs[mt + quad * 4 + r] * bv;
        #pragma unroll
        for (int ks = 0; ks < 2; ++ks) {
            v8h af = *(const v8h*)&u.k2.t1b[(mt + l15) * FST + ks * 32 + fko];
            v8h bf = *(const v8h*)&g_W1bT[(nt + l15) * HD + ks * 32 + fko];
            axp = __builtin_amdgcn_mfma_f32_16x16x32_f16(af, bf, axp, 0, 0, 0);
        }
    }
    __syncthreads();    // SPb (aliases cnt) fully read before phase 3 zeroes

    // ---- phase 3: dense-A slabs + MFMA AS/Ap/G ----
    float sumA2 = 0.f;
    v4f ap = {0.f, 0.f, 0.f, 0.f};
    v4f ag = {0.f, 0.f, 0.f, 0.f};

    for (int ch = 0; ch < 4; ++ch) {
        for (int i = tid; i < 64 * 128; i += 1024) u.a.cnt[i] = 0u;
        __syncthreads();

        int rlo = ch << 6;
        #pragma unroll
        for (int j = 0; j < 4; ++j) {
            unsigned c = cellr[j];
            int sr = (int)(c >> 8) - rlo;
            if ((unsigned)sr < 64u) {
                int d = c & 255u;
                atomicAdd(&u.a.cnt[SW_AW(sr, d >> 1)],
                          (d & 1) ? 0x10000u : 1u);
            }
        }
        __syncthreads();

        // sum(A^2) partial + in-place convert counts -> f16
        for (int i = tid; i < 64 * 128; i += 1024) {
            unsigned v = u.a.cnt[i];
            float m0 = (float)(v & 0xffffu), m1 = (float)(v >> 16);
            sumA2 += m0 * m0 + m1 * m1;
            union { unsigned uu; _Float16 h[2]; } cv;
            cv.h[0] = (_Float16)m0; cv.h[1] = (_Float16)m1;
            u.a.cnt[i] = cv.uu;
        }
        __syncthreads();

        const _Float16* Af = (const _Float16*)u.a.cnt;

        // AS_slab = A_slab @ S  -> T1T (aux region; xagg dead)
        {
            const int ar = mt + l15, br = nt + l15;
            v4f acc = {0.f, 0.f, 0.f, 0.f};
            #pragma unroll
            for (int ks = 0; ks < 8; ++ks) {
                v8h af = *(const v8h*)&Af[SW_AH(ar, ks * 32 + fko)];
                v8h bf = *(const v8h*)&ST[SW_ST(br, ks * 32 + fko)];
                acc = __builtin_amdgcn_mfma_f32_16x16x32_f16(af, bf, acc, 0, 0, 0);
            }
            int c = nt + l15;
            #pragma unroll
            for (int r = 0; r < 4; ++r)
                T1T[c * FST + mt + quad * 4 + r] = (_Float16)acc[r];
        }
        __syncthreads();

        // Ap += S_slab^T @ AS_slab; G += S^T S (slab K-range)
        {
            const int ar = mt + l15, br = nt + l15;
            #pragma unroll
            for (int ks = 0; ks < 2; ++ks) {
                int ko = (ch << 6) + ks * 32 + fko;
                v8h af = *(const v8h*)&ST[SW_ST(ar, ko)];
                v8h bt = *(const v8h*)&T1T[br * FST + ks * 32 + fko];
                v8h bs = *(const v8h*)&ST[SW_ST(br, ko)];
                ap = __builtin_amdgcn_mfma_f32_16x16x32_f16(af, bt, ap, 0, 0, 0);
                ag = __builtin_amdgcn_mfma_f32_16x16x32_f16(af, bs, ag, 0, 0, 0);
            }
        }
        __syncthreads();    // cnt reused next slab
    }

    // scalars + f16 Ap / xp^T into tail buffers
    float tr = 0.f, g2 = 0.f;
    {
        int c = nt + l15;
        #pragma unroll
        for (int r = 0; r < 4; ++r) {
            int k = mt + quad * 4 + r;
            u.b.Apf_tf[k * FST + c] = (_Float16)ap[r];
            u.b.xpT[c * FST + k] = (_Float16)axp[r];
            if (k < KC && c < KC) {
                if (k == c) tr += ap[r];
                g2 += ag[r] * ag[r];
            }
        }
    }

    float rA = blockReduceN(sumA2, red, 16);   // internal barriers fence u.b
    float rT = blockReduceN(tr, red, 16);
    float rG = blockReduceN(g2, red, 16);
    if (tid == 0) {
        atomicAdd(&ws[0], rA);
        atomicAdd(&ws[2], rT);
        atomicAdd(&ws[3], rG);
    }
    __syncthreads();

    // ---- MFMA tail: h2 = xp + Ap @ xp, scaled by 1/256 ----
    {
        v4f hacc = axp;
        #pragma unroll
        for (int ks = 0; ks < 2; ++ks) {
            v8h af = *(const v8h*)&u.b.Apf_tf[(mt + l15) * FST + ks * 32 + fko];
            v8h bf = *(const v8h*)&u.b.xpT[(nt + l15) * FST + ks * 32 + fko];
            hacc = __builtin_amdgcn_mfma_f32_16x16x32_f16(af, bf, hacc, 0, 0, 0);
        }
        int d = nt + l15;
        #pragma unroll
        for (int r = 0; r < 4; ++r)
            u.b.h2f[(mt + quad * 4 + r) * FST + d] = (_Float16)(hacc[r] * TSC);
    }
    __syncthreads();

    // t*s = relu(h2s @ W2a + s*b2a) -> overwrites Apf (reads done pre-barrier)
    {
        float bv = b2a[nt + l15] * TSC;
        v4f tacc = {bv, bv, bv, bv};
        #pragma unroll
        for (int ks = 0; ks < 2; ++ks) {
            v8h af = *(const v8h*)&u.b.h2f[(mt + l15) * FST + ks * 32 + fko];
            v8h bf = *(const v8h*)&g_W2aT[(nt + l15) * 64 + ks * 32 + fko];
            tacc = __builtin_amdgcn_mfma_f32_16x16x32_f16(af, bf, tacc, 0, 0, 0);
        }
        int d2 = nt + l15;
        #pragma unroll
        for (int r = 0; r < 4; ++r)
            u.b.Apf_tf[(mt + quad * 4 + r) * FST + d2] = (_Float16)fmaxf(tacc[r], 0.f);
    }
    __syncthreads();

    // h3 = (t*s)@W2b * 256 + b2b; fold mean over k and Wl in fp32
    float l0 = 0.f, l1 = 0.f;
    {
        v4f oacc = {0.f, 0.f, 0.f, 0.f};
        #pragma unroll
        for (int ks = 0; ks < 2; ++ks) {
            v8h af = *(const v8h*)&u.b.Apf_tf[(mt + l15) * FST + ks * 32 + fko];
            v8h bf = *(const v8h*)&g_W2bT[(nt + l15) * 64 + ks * 32 + fko];
            oacc = __builtin_amdgcn_mfma_f32_16x16x32_f16(af, bf, oacc, 0, 0, 0);
        }
        int j = nt + l15;
        float bv = b2b[j];
        float wl0 = Wl[j * 2], wl1 = Wl[j * 2 + 1];
        #pragma unroll
        for (int r = 0; r < 4; ++r) {
            int k = mt + quad * 4 + r;
            if (k < KC) {
                float h3v = oacc[r] * TSCI + bv;
                l0 += h3v * wl0; l1 += h3v * wl1;
            }
        }
    }

    float rl0 = blockReduceN(l0, red, 16);
    float rl1 = blockReduceN(l1, red, 16);
    if (tid == 0) {
        float g0 = bl[0] + rl0 * (1.f / KC);
        float g1 = bl[1] + rl1 * (1.f / KC);
        float mm = fmaxf(g0, g1);
        float lse = mm + logf(expf(g0 - mm) + expf(g1 - mm));
        out[2 * g]     = g0 - lse;
        out[2 * g + 1] = g1 - lse;
    }
}

extern "C" void kernel_launch(void* const* d_in, const int* in_sizes, int n_in,
                              void* d_out, int out_size, void* d_ws, size_t ws_size,
                              hipStream_t stream) {
    const float* x    = (const float*)d_in[0];
    const float* W1a  = (const float*)d_in[1];
    const float* b1a  = (const float*)d_in[2];
    const float* W1b  = (const float*)d_in[3];
    const float* b1b  = (const float*)d_in[4];
    const float* Wp   = (const float*)d_in[5];
    const float* bp   = (const float*)d_in[6];
    const float* W2a  = (const float*)d_in[7];
    const float* b2a  = (const float*)d_in[8];
    const float* W2b  = (const float*)d_in[9];
    const float* b2b  = (const float*)d_in[10];
    const float* Wl   = (const float*)d_in[11];
    const float* bl   = (const float*)d_in[12];
    const int*   eidx = (const int*)d_in[13];   // [2, E] int32
    float* out = (float*)d_out;
    float* ws  = (float*)d_ws;

    kw_conv<<<16, 256, 0, stream>>>(W1b, Wp, W2a, W2b, b1b, bp, ws);
    mega<<<NG, 1024, 0, stream>>>(eidx, eidx + ETOT, x,
                                  W1a, b1a, b1b,
                                  b2a, b2b, Wl, bl, out, ws);
    finalize_k<<<1, 64, 0, stream>>>(ws, out);
}